// Round 12
// baseline (422.472 us; speedup 1.0000x reference)
//
#include <hip/hip_runtime.h>
#include <stdint.h>

// ---------------------------------------------------------------------------
// VQ codebook lookup, MI355X — fp32-quantization-replicating argmin.
//  L1: k0    — w2 (fl32 of f64), C0 = fl32(0.5+0.5*w2), zero shard counters
//  L2: k0b+k3 fused — blocks 0-127: transpose W -> fragment-major fp16(-32*W);
//      blocks 128+: codebook min pairwise distance (LDS-staged, padded rows)
//  L3: k1    — MFMA ranking (fp16 16x16x32). NO LDS, NO barriers: Whf is
//      L2-resident (512 KB/XCD); each wave streams A-fragments from L2 into
//      ping-pong register buffers prefetched one full tile (~900 cyc) ahead.
//      Coalesced: lane's fragment = ct*512 + kc*64 + lane -> 1KB/instr.
//      c0 register-prefetched from L1-hot table. Waves free-run (no 10K-cyc
//      period convoy, no LDS-pipe load). Branchless epilogue, 64-shard
//      fixup list, one batched atomic per wave.
//  L4: k2    — fixup (np-replicated d = fl32(fl32(x2+w2)-fl32(2*dot)),
//      correctly-rounded f32 dots, lowest-index ties; 4-way ILP butterflies;
//      full-scan inner loop 4-way ILP); block 0 writes sqrt(minbits).
// ---------------------------------------------------------------------------

typedef _Float16 h8 __attribute__((ext_vector_type(8)));
typedef float f32x4 __attribute__((ext_vector_type(4)));
typedef unsigned long long u64;

#define NROWS (32*4096)
#define DDIM 256
#define KCODES 1024
#define XSCALE (1.0f/32.0f)
#define WSCALE (-32.0f)
#define EPS 1.2e-4f
#define NT 2
#define NSHARD 64

// ws layout (bytes)
#define WS_MIN   0
#define WS_CNTS  4096                    // 64 counters, 64 B stride (16 ints)
#define WS_W2    8192
#define WS_C0    12288
#define WS_WH    16384                   // 512 KB fragment-major fp16 W
#define WS_LIST  540672                  // sharded entries: 2 x int4 = 32 B

static __device__ __forceinline__ unsigned umn(unsigned a, unsigned b){ return a<b?a:b; }
static __device__ __forceinline__ unsigned umx(unsigned a, unsigned b){ return a>b?a:b; }

// insert x into ascending sorted triple (u32)
#define PUSH3(t1,t2,t3,x) do { unsigned _lo=umn(t1,x), _hi=umx(t1,x); t1=_lo; \
    unsigned _lo2=umn(t2,_hi), _hi2=umx(t2,_hi); t2=_lo2; t3=umn(t3,_hi2); } while(0)

// insert x into ascending sorted quad (u64)
#define PUSH4(t1,t2,t3,t4,x) do { \
    u64 _a = (t1<(x))?(x):t1; t1 = (t1<(x))?t1:(x); \
    u64 _b = (t2<_a)?_a:t2;   t2 = (t2<_a)?t2:_a;   \
    u64 _c = (t3<_b)?_b:t3;   t3 = (t3<_b)?t3:_b;   \
    t4 = (t4<_c)?t4:_c; } while(0)

static __device__ __forceinline__ u64 shflx_u64(u64 v, int m) {
  int lo = __shfl_xor((int)(unsigned)(v & 0xffffffffULL), m, 64);
  int hi = __shfl_xor((int)(unsigned)(v >> 32), m, 64);
  return ((u64)(unsigned)hi << 32) | (u64)(unsigned)lo;
}
static __device__ __forceinline__ u64 u64mn(u64 a, u64 b){ return a<b?a:b; }
static __device__ __forceinline__ double shflx_f64(double v, int m) {
  u64 b = __double_as_longlong(v);
  return __longlong_as_double((long long)shflx_u64((u64)b, m));
}

// ---------------------------------------------------------------- K0: tables
__global__ __launch_bounds__(256) void k0_prep(const float* __restrict__ W,
    float* __restrict__ w2tab, float* __restrict__ c0tab,
    int* __restrict__ cnts, unsigned* __restrict__ minbits) {
  int wave = threadIdx.x >> 6, lane = threadIdx.x & 63;
  int k = blockIdx.x * 4 + wave;
  const float* wr = W + (size_t)k * DDIM;
  f32x4 a = *(const f32x4*)(wr + lane*4);
  double p = (double)a[0]*a[0] + (double)a[1]*a[1] + (double)a[2]*a[2] + (double)a[3]*a[3];
  #pragma unroll
  for (int off = 32; off; off >>= 1) p += __shfl_xor(p, off, 64);
  if (lane == 0) { w2tab[k] = (float)p; c0tab[k] = (float)(0.5 + 0.5*p); }
  if (blockIdx.x == 0) {
    if (threadIdx.x < NSHARD) cnts[threadIdx.x * 16] = 0;   // 64 B-strided counters
    if (threadIdx.x == NSHARD) *minbits = 0x7F800000u;
  }
}

// ------------------------------- K0b + K3 fused (independent block groups)
// blocks 0-127: Whf fragment f_lin = ct*512 + kc*64 + hi*16 + cc holds
//               fp16(-32*W[ct*16+cc][kc*32+hi*8 .. +7])
// blocks 128-639: codebook min pairwise distance (i-tile 32 x j-tile 64)
#define LDI 260
__global__ __launch_bounds__(256) void k0b_k3(const float* __restrict__ W,
    _Float16* __restrict__ Whf, const float* __restrict__ w2tab,
    unsigned* __restrict__ minbits) {
  __shared__ float si[32*LDI];                      // ~33 KB
  __shared__ float sj[16*LDI];                      // ~17 KB
  __shared__ float wmin[4];
  if (blockIdx.x < 128) {                           // ---- k0b: transpose
    int t = blockIdx.x * 256 + threadIdx.x;         // 0..32767
    int ct = t >> 9, f = t & 511;
    int kc = f >> 6, hi = (f >> 4) & 3, cc = f & 15;
    const float* src = W + (size_t)(ct*16 + cc) * DDIM + kc*32 + hi*8;
    f32x4 a = *(const f32x4*)src;
    f32x4 b = *(const f32x4*)(src + 4);
    h8 h;
    h[0]=(_Float16)(a[0]*WSCALE); h[1]=(_Float16)(a[1]*WSCALE);
    h[2]=(_Float16)(a[2]*WSCALE); h[3]=(_Float16)(a[3]*WSCALE);
    h[4]=(_Float16)(b[0]*WSCALE); h[5]=(_Float16)(b[1]*WSCALE);
    h[6]=(_Float16)(b[2]*WSCALE); h[7]=(_Float16)(b[3]*WSCALE);
    *(h8*)(Whf + (size_t)t * 8) = h;                // coalesced 16B/thread
    return;
  }
  // ---- k3: codebook distance
  int bid = blockIdx.x - 128;
  int bi = bid >> 4, bj = bid & 15;
  int i0 = bi * 32, j0 = bj * 64;
  for (int v = threadIdx.x; v < 32*64; v += 256) {  // coalesced si load
    int r = v >> 6, c = (v & 63) * 4;
    *(f32x4*)&si[r*LDI + c] = *(const f32x4*)(W + (size_t)(i0+r)*DDIM + c);
  }
  int ti = (threadIdx.x >> 4) * 2;                  // 2 i-rows
  int tj = threadIdx.x & 15;                        // 1 j-row per chunk
  float lmin = __uint_as_float(0x7F800000u);
  for (int ch = 0; ch < 4; ++ch) {
    __syncthreads();                                // sj safe to overwrite (+si ready)
    for (int v = threadIdx.x; v < 16*64; v += 256) {
      int r = v >> 6, c = (v & 63) * 4;
      *(f32x4*)&sj[r*LDI + c] = *(const f32x4*)(W + (size_t)(j0 + ch*16 + r)*DDIM + c);
    }
    __syncthreads();
    float d0 = 0.f, d1 = 0.f;
    for (int d = 0; d < DDIM; d += 4) {
      f32x4 jv = *(const f32x4*)&sj[tj*LDI + d];
      f32x4 a0 = *(const f32x4*)&si[ti*LDI + d];
      f32x4 a1 = *(const f32x4*)&si[(ti+1)*LDI + d];
      d0 += a0[0]*jv[0] + a0[1]*jv[1] + a0[2]*jv[2] + a0[3]*jv[3];
      d1 += a1[0]*jv[0] + a1[1]*jv[1] + a1[2]*jv[2] + a1[3]*jv[3];
    }
    int gj = j0 + ch*16 + tj;
    int gi0 = i0 + ti, gi1 = gi0 + 1;
    if (gi0 != gj) lmin = fminf(lmin, fmaxf(w2tab[gi0] + w2tab[gj] - 2.0f*d0, 0.0f));
    if (gi1 != gj) lmin = fminf(lmin, fmaxf(w2tab[gi1] + w2tab[gj] - 2.0f*d1, 0.0f));
  }
  #pragma unroll
  for (int off = 32; off; off >>= 1) lmin = fminf(lmin, __shfl_xor(lmin, off, 64));
  if ((threadIdx.x & 63) == 0) wmin[threadIdx.x >> 6] = lmin;
  __syncthreads();
  if (threadIdx.x == 0) {
    float m = fminf(fminf(wmin[0], wmin[1]), fminf(wmin[2], wmin[3]));
    atomicMin(minbits, __float_as_uint(m));
  }
}

// ---------------------------------------------------------------- K1: main
// 256 thr = 4 waves; wave owns 32 x-rows (2 tiles of 16); 64 code-tiles.
// NO LDS / NO barriers: af + c0 register-prefetched one tile ahead from L2.
// A = W' (codes), B = X (rows): C[code][xrow], lane: col=xrow=l&15, code=(l>>4)*4+r.
#define COMPUTE_HALF(CT, AF, C0)                                                      \
  {                                                                                   \
    f32x4 acc0 = (C0), acc1 = (C0);             /* acc init = 0.5 + 0.5*w2 */         \
    __builtin_amdgcn_s_setprio(1);                                                    \
    _Pragma("unroll")                                                                 \
    for (int kc = 0; kc < 8; ++kc) {                                                  \
      acc0 = __builtin_amdgcn_mfma_f32_16x16x32_f16(AF[kc], xf[0][kc], acc0, 0,0,0);  \
      acc1 = __builtin_amdgcn_mfma_f32_16x16x32_f16(AF[kc], xf[1][kc], acc1, 0,0,0);  \
    }                                                                                 \
    __builtin_amdgcn_s_setprio(0);                                                    \
    _Pragma("unroll")                                                                 \
    for (int r = 0; r < 4; ++r) {                                                     \
      /* s = 0.5+0.5w2-dot in (0.44,0.56): positive -> uint-monotone.       */        \
      /* low 6 bits hold ct (score quantum 64 ULP(0.5) = 3.8e-6).           */        \
      unsigned k0 = (__float_as_uint(acc0[r]) & ~63u) | (unsigned)(CT);               \
      unsigned k1v = (__float_as_uint(acc1[r]) & ~63u) | (unsigned)(CT);              \
      PUSH3(m1[0][r], m2[0][r], m3[0][r], k0);                                        \
      PUSH3(m1[1][r], m2[1][r], m3[1][r], k1v);                                       \
    }                                                                                 \
  }

__global__ __launch_bounds__(256, 3) void k1_main(const float* __restrict__ X,
    const _Float16* __restrict__ Whf, const float* __restrict__ c0tab,
    const float* __restrict__ W, float* __restrict__ q,
    int4* __restrict__ list, int* __restrict__ cnts, int shard_cap) {
  const int wave = threadIdx.x >> 6, lane = threadIdx.x & 63;
  const int col = lane & 15, hi = lane >> 4;
  const int rowbase = blockIdx.x * (64*NT) + wave * (16*NT);

  // X rows -> fp16 fragments (B: col=l&15, k = (l>>4)*8 + j within 32-chunk)
  h8 xf[NT][8];
  #pragma unroll
  for (int t = 0; t < NT; ++t) {
    const float* xr = X + (size_t)(rowbase + t*16 + col) * DDIM + hi*8;
    #pragma unroll
    for (int kc = 0; kc < 8; ++kc) {
      f32x4 a = *(const f32x4*)(xr + kc*32);
      f32x4 b = *(const f32x4*)(xr + kc*32 + 4);
      h8 h;
      h[0]=(_Float16)(a[0]*XSCALE); h[1]=(_Float16)(a[1]*XSCALE);
      h[2]=(_Float16)(a[2]*XSCALE); h[3]=(_Float16)(a[3]*XSCALE);
      h[4]=(_Float16)(b[0]*XSCALE); h[5]=(_Float16)(b[1]*XSCALE);
      h[6]=(_Float16)(b[2]*XSCALE); h[7]=(_Float16)(b[3]*XSCALE);
      xf[t][kc] = h;
    }
  }

  unsigned m1[NT][4], m2[NT][4], m3[NT][4];  // per (tile,reg) slot top-3 keys
  #pragma unroll
  for (int t = 0; t < NT; ++t)
    #pragma unroll
    for (int r = 0; r < 4; ++r) { m1[t][r]=0xFFFFFFFFu; m2[t][r]=0xFFFFFFFFu; m3[t][r]=0xFFFFFFFFu; }

  // lane's fragment for (ct,kc) sits at Whf + (ct*512 + kc*64 + lane)*8:
  // consecutive lanes -> consecutive 16B -> fully coalesced 1KB/load.
  const _Float16* wbase = Whf + (size_t)lane * 8;
  const float* c0p = c0tab + hi*4;

  h8 afA[8], afB[8];
  f32x4 c0A, c0B;
  #pragma unroll
  for (int kc = 0; kc < 8; ++kc) afA[kc] = *(const h8*)(wbase + (size_t)kc*64*8);
  c0A = *(const f32x4*)(c0p);

  for (int p = 0; p < 32; ++p) {
    const int ct0 = 2*p, ct1 = 2*p + 1;
    {                                              // prefetch tile ct1 -> B regs
      const _Float16* nb = wbase + (size_t)ct1*512*8;
      #pragma unroll
      for (int kc = 0; kc < 8; ++kc) afB[kc] = *(const h8*)(nb + (size_t)kc*64*8);
      c0B = *(const f32x4*)(c0p + ct1*16);
    }
    COMPUTE_HALF(ct0, afA, c0A);
    {                                              // prefetch tile ct1+1 -> A regs
      const int nt = (ct1 + 1 > 63) ? 63 : ct1 + 1;  // dup-load at tail, harmless
      const _Float16* nb = wbase + (size_t)nt*512*8;
      #pragma unroll
      for (int kc = 0; kc < 8; ++kc) afA[kc] = *(const h8*)(nb + (size_t)kc*64*8);
      c0A = *(const f32x4*)(c0p + nt*16);
    }
    COMPUTE_HALF(ct1, afB, c0B);
  }

  // ---- merge: slot top-3 -> u64 (scorebits<<32 | code) -> row top-4 ----
  u64 T1[NT], T2[NT], T3[NT], T4[NT];
  #pragma unroll
  for (int t = 0; t < NT; ++t) {
    u64 t1=~0ULL, t2=~0ULL, t3=~0ULL, t4=~0ULL;
    #pragma unroll
    for (int r = 0; r < 4; ++r) {
      unsigned ks[3] = { m1[t][r], m2[t][r], m3[t][r] };
      #pragma unroll
      for (int m = 0; m < 3; ++m) {
        unsigned key = ks[m];
        unsigned code = (key & 63u)*16u + (unsigned)(hi*4 + r);
        u64 k64 = ((u64)(key & ~63u) << 32) | code;
        PUSH4(t1,t2,t3,t4,k64);
      }
    }
    #pragma unroll
    for (int dd = 16; dd <= 32; dd <<= 1) {
      u64 o1=shflx_u64(t1,dd), o2=shflx_u64(t2,dd), o3=shflx_u64(t3,dd), o4=shflx_u64(t4,dd);
      PUSH4(t1,t2,t3,t4,o1); PUSH4(t1,t2,t3,t4,o2);
      PUSH4(t1,t2,t3,t4,o3); PUSH4(t1,t2,t3,t4,o4);
    }
    T1[t]=t1; T2[t]=t2; T3[t]=t3; T4[t]=t4;
  }

  // Phase 1: per-row slow flags (wave-uniform bitmask, 1 bit per row c=0..15)
  unsigned smask[NT]; unsigned win[NT];
  #pragma unroll
  for (int t = 0; t < NT; ++t) {
    float f1 = __uint_as_float((unsigned)(T1[t]>>32));
    float f2 = __uint_as_float((unsigned)(T2[t]>>32));
    win[t] = (unsigned)T1[t] & 1023u;
    smask[t] = (unsigned)(__ballot(f2 - f1 <= EPS) & 0xFFFFull);
  }

  // Phase 2: one batched atomic per wave; single-lane entry stores (rare)
  int nslow = __popc(smask[0]) + __popc(smask[1]);
  const int shard = (blockIdx.x * 4 + wave) & (NSHARD - 1);
  int* cnt = cnts + shard * 16;
  int base = 0;
  if (nslow) {
    if (lane == 0) base = atomicAdd(cnt, nslow);
    base = __shfl(base, 0, 64);
  }
  int idx = 0;
  #pragma unroll
  for (int t = 0; t < NT; ++t) {
    unsigned m = smask[t];
    while (m) {
      int c = __builtin_ctz(m); m &= m - 1;
      int pos = base + idx;
      if (pos < shard_cap && lane == c) {
        unsigned c1 = (unsigned)T1[t] & 1023u, c2 = (unsigned)T2[t] & 1023u;
        unsigned c3 = (unsigned)T3[t] & 1023u, c4 = (unsigned)T4[t] & 1023u;
        size_t e = ((size_t)shard * shard_cap + pos) * 2;
        list[e]   = make_int4(rowbase + t*16 + c, (int)(unsigned)(T1[t]>>32),
                              (int)(unsigned)(T2[t]>>32), (int)(unsigned)(T3[t]>>32));
        list[e+1] = make_int4((int)(unsigned)(T4[t]>>32),
                              (int)(c1 | (c2<<10) | (c3<<20)), (int)c4, 0);
      }
      idx++;
    }
  }

  // Phase 3: pre-broadcast all 32 winners, then independent pipelined gathers.
  // Slow rows get the provisional winner; k2 overwrites them.
  unsigned wbc[NT][16];
  #pragma unroll
  for (int t = 0; t < NT; ++t)
    #pragma unroll
    for (int c = 0; c < 16; ++c)
      wbc[t][c] = (unsigned)__shfl((int)win[t], c, 64);
  #pragma unroll
  for (int t = 0; t < NT; ++t)
    #pragma unroll
    for (int c = 0; c < 16; ++c) {
      f32x4 wv = *(const f32x4*)(W + (size_t)wbc[t][c]*DDIM + lane*4);
      *(f32x4*)(q + (size_t)(rowbase + t*16 + c)*DDIM + lane*4) = wv;
    }
}

// ---------------------------------------------------------------- K2: fixup (+k4)
__global__ __launch_bounds__(256) void k2_fix(const float* __restrict__ X,
    const float* __restrict__ W, const float* __restrict__ w2tab,
    float* __restrict__ q, const int4* __restrict__ list,
    const int* __restrict__ cnts, int shard_cap,
    const unsigned* __restrict__ minbits, float* __restrict__ outscalar) {
  if (blockIdx.x == 0 && threadIdx.x == 0)          // k3 done (prior launch)
    *outscalar = sqrtf(__uint_as_float(*minbits));
  __shared__ float xs[4][DDIM];
  const int wave = threadIdx.x >> 6, lane = threadIdx.x & 63;
  const int wgid = blockIdx.x * 4 + wave;
  const int shard = wgid & (NSHARD - 1);
  const int start = wgid >> 6;                    // NSHARD==64
  const int step  = (gridDim.x * 4) >> 6;
  int cnt = cnts[shard * 16]; if (cnt > shard_cap) cnt = shard_cap;

  for (int i = start; i < cnt; i += step) {
    size_t e = ((size_t)shard * shard_cap + i) * 2;
    int4 e0 = list[e], e1 = list[e + 1];
    int row = e0.x;
    float f1 = __uint_as_float((unsigned)e0.y);
    float f2 = __uint_as_float((unsigned)e0.z);
    float f3 = __uint_as_float((unsigned)e0.w);
    float f4 = __uint_as_float((unsigned)e1.x);
    unsigned cpack = (unsigned)e1.y;

    const float* xr = X + (size_t)row * DDIM;
    f32x4 xv = *(const f32x4*)(xr + lane*4);
    // x2 like np: square in fp32, sum exactly (f64), round once
    double x2d = (double)(xv[0]*xv[0]) + (double)(xv[1]*xv[1])
               + (double)(xv[2]*xv[2]) + (double)(xv[3]*xv[3]);

    if (f4 - f1 <= EPS) {
      // full scan: every code, f64 dot (4-way ILP), np-replicated quantization
      #pragma unroll
      for (int off = 32; off; off >>= 1) x2d += shflx_f64(x2d, off);
      float x2f = (float)x2d;
      *(f32x4*)&xs[wave][lane*4] = xv;
      u64 best = ~0ULL;
      for (int c = lane; c < KCODES; c += 64) {
        const float* wr = W + (size_t)c * DDIM;
        double p0 = 0.0, p1 = 0.0, p2 = 0.0, p3 = 0.0;   // 4 independent chains
        for (int d = 0; d < DDIM; d += 16) {
          f32x4 w0 = *(const f32x4*)(wr + d);
          f32x4 w1 = *(const f32x4*)(wr + d + 4);
          f32x4 w2 = *(const f32x4*)(wr + d + 8);
          f32x4 w3 = *(const f32x4*)(wr + d + 12);
          p0 += (double)w0[0]*xs[wave][d]    + (double)w0[1]*xs[wave][d+1]
              + (double)w0[2]*xs[wave][d+2]  + (double)w0[3]*xs[wave][d+3];
          p1 += (double)w1[0]*xs[wave][d+4]  + (double)w1[1]*xs[wave][d+5]
              + (double)w1[2]*xs[wave][d+6]  + (double)w1[3]*xs[wave][d+7];
          p2 += (double)w2[0]*xs[wave][d+8]  + (double)w2[1]*xs[wave][d+9]
              + (double)w2[2]*xs[wave][d+10] + (double)w2[3]*xs[wave][d+11];
          p3 += (double)w3[0]*xs[wave][d+12] + (double)w3[1]*xs[wave][d+13]
              + (double)w3[2]*xs[wave][d+14] + (double)w3[3]*xs[wave][d+15];
        }
        float dotf = (float)((p0 + p1) + (p2 + p3));
        float dval = (x2f + w2tab[c]) - 2.0f*dotf;
        best = u64mn(best, ((u64)__float_as_uint(dval) << 32) | (unsigned)c);
      }
      #pragma unroll
      for (int off = 32; off; off >>= 1) best = u64mn(best, shflx_u64(best, off));
      unsigned win = (unsigned)best & 1023u;
      f32x4 wv = *(const f32x4*)(W + (size_t)win*DDIM + lane*4);
      *(f32x4*)(q + (size_t)row*DDIM + lane*4) = wv;
    } else {
      // always rescore 3 candidates (pad duplicates) with 4-way-ILP butterflies
      unsigned ca = cpack & 1023u;
      unsigned cb = (f2 - f1 <= EPS) ? ((cpack>>10) & 1023u) : ca;
      unsigned cc = (f3 - f1 <= EPS) ? ((cpack>>20) & 1023u) : ca;
      f32x4 wa = *(const f32x4*)(W + (size_t)ca*DDIM + lane*4);
      f32x4 wb = *(const f32x4*)(W + (size_t)cb*DDIM + lane*4);
      f32x4 wc = *(const f32x4*)(W + (size_t)cc*DDIM + lane*4);
      double da = (double)xv[0]*wa[0] + (double)xv[1]*wa[1]
                + (double)xv[2]*wa[2] + (double)xv[3]*wa[3];
      double db = (double)xv[0]*wb[0] + (double)xv[1]*wb[1]
                + (double)xv[2]*wb[2] + (double)xv[3]*wb[3];
      double dc = (double)xv[0]*wc[0] + (double)xv[1]*wc[1]
                + (double)xv[2]*wc[2] + (double)xv[3]*wc[3];
      #pragma unroll
      for (int off = 32; off; off >>= 1) {          // 4 interleaved chains
        x2d += shflx_f64(x2d, off);
        da  += shflx_f64(da,  off);
        db  += shflx_f64(db,  off);
        dc  += shflx_f64(dc,  off);
      }
      float x2f = (float)x2d;
      float va = (x2f + w2tab[ca]) - 2.0f*(float)da;   // np's expression, fp32
      float vb = (x2f + w2tab[cb]) - 2.0f*(float)db;
      float vc = (x2f + w2tab[cc]) - 2.0f*(float)dc;
      u64 best = ((u64)__float_as_uint(va) << 32) | ca;  // tie -> lower index
      best = u64mn(best, ((u64)__float_as_uint(vb) << 32) | cb);
      best = u64mn(best, ((u64)__float_as_uint(vc) << 32) | cc);
      unsigned win = (unsigned)best & 1023u;
      f32x4 wv = *(const f32x4*)(W + (size_t)win*DDIM + lane*4);
      *(f32x4*)(q + (size_t)row*DDIM + lane*4) = wv;
    }
  }
}

// ---------------------------------------------------------------- launch
extern "C" void kernel_launch(void* const* d_in, const int* in_sizes, int n_in,
                              void* d_out, int out_size, void* d_ws, size_t ws_size,
                              hipStream_t stream) {
  const float* X = (const float*)d_in[0];
  const float* W = (const float*)d_in[1];
  float* out = (float*)d_out;
  char* ws = (char*)d_ws;

  unsigned* minbits = (unsigned*)(ws + WS_MIN);
  int* cnts = (int*)(ws + WS_CNTS);
  float* w2tab = (float*)(ws + WS_W2);
  float* c0tab = (float*)(ws + WS_C0);
  _Float16* Whf = (_Float16*)(ws + WS_WH);
  int4* list = (int4*)(ws + WS_LIST);

  long long cap_ll = ((long long)ws_size - (long long)WS_LIST) / (NSHARD * 32);
  if (cap_ll < 0) cap_ll = 0;
  if (cap_ll > NROWS) cap_ll = NROWS;
  int shard_cap = (int)cap_ll;

  k0_prep<<<KCODES/4, 256, 0, stream>>>(W, w2tab, c0tab, cnts, minbits);
  k0b_k3<<<128 + 512, 256, 0, stream>>>(W, Whf, w2tab, minbits);
  k1_main<<<NROWS/(64*NT), 256, 0, stream>>>(X, Whf, c0tab, W, out, list, cnts, shard_cap);
  k2_fix<<<1024, 256, 0, stream>>>(X, W, w2tab, out, list, cnts, shard_cap,
                                   minbits, out + (size_t)NROWS*DDIM);
}

// Round 13
// 210.715 us; speedup vs baseline: 2.0049x; 2.0049x over previous
//
#include <hip/hip_runtime.h>
#include <stdint.h>

// ---------------------------------------------------------------------------
// VQ codebook lookup, MI355X — fp32-quantization-replicating argmin.
//  L1: k0    — w2 (fl32 of f64), C0 = fl32(0.5+0.5*w2), zero shard counters
//  L2: k0b+k3 fused — blocks 0-127: transpose W -> fragment-major fp16(-32*W);
//      blocks 128+: codebook min pairwise distance (LDS-staged, padded rows)
//  L3: k1    — MFMA ranking (fp16 16x16x32). QUAD-PERIODS: 16 periods x 4
//      code-tiles; 512-thr/8-wave blocks, grid 512 = exactly 2 blocks/CU.
//      8-buf LDS ring (2 quads) + c0 = 68 KB. Stage quad p+1 at period top,
//      ONE vmcnt(0)+barrier per period (16 convoys instead of 32/64 — the
//      cross-round data shows wall time ~ 10.5K cycles x period count).
//      Branchless epilogue, 64-shard fixup list, one batched atomic/wave.
//  L4: k2    — fixup (np-replicated d = fl32(fl32(x2+w2)-fl32(2*dot)),
//      correctly-rounded f32 dots, lowest-index ties; 4-way ILP butterflies;
//      full-scan inner loop 4-way ILP); block 0 writes sqrt(minbits).
// ---------------------------------------------------------------------------

typedef _Float16 h8 __attribute__((ext_vector_type(8)));
typedef float f32x4 __attribute__((ext_vector_type(4)));
typedef unsigned long long u64;

#define NROWS (32*4096)
#define DDIM 256
#define KCODES 1024
#define XSCALE (1.0f/32.0f)
#define WSCALE (-32.0f)
#define EPS 1.2e-4f
#define NT 2
#define NSHARD 64

// ws layout (bytes)
#define WS_MIN   0
#define WS_CNTS  4096                    // 64 counters, 64 B stride (16 ints)
#define WS_W2    8192
#define WS_C0    12288
#define WS_WH    16384                   // 512 KB fragment-major fp16 W
#define WS_LIST  540672                  // sharded entries: 2 x int4 = 32 B

static __device__ __forceinline__ unsigned umn(unsigned a, unsigned b){ return a<b?a:b; }
static __device__ __forceinline__ unsigned umx(unsigned a, unsigned b){ return a>b?a:b; }

// insert x into ascending sorted triple (u32)
#define PUSH3(t1,t2,t3,x) do { unsigned _lo=umn(t1,x), _hi=umx(t1,x); t1=_lo; \
    unsigned _lo2=umn(t2,_hi), _hi2=umx(t2,_hi); t2=_lo2; t3=umn(t3,_hi2); } while(0)

// insert x into ascending sorted quad (u64)
#define PUSH4(t1,t2,t3,t4,x) do { \
    u64 _a = (t1<(x))?(x):t1; t1 = (t1<(x))?t1:(x); \
    u64 _b = (t2<_a)?_a:t2;   t2 = (t2<_a)?t2:_a;   \
    u64 _c = (t3<_b)?_b:t3;   t3 = (t3<_b)?t3:_b;   \
    t4 = (t4<_c)?t4:_c; } while(0)

static __device__ __forceinline__ u64 shflx_u64(u64 v, int m) {
  int lo = __shfl_xor((int)(unsigned)(v & 0xffffffffULL), m, 64);
  int hi = __shfl_xor((int)(unsigned)(v >> 32), m, 64);
  return ((u64)(unsigned)hi << 32) | (u64)(unsigned)lo;
}
static __device__ __forceinline__ u64 u64mn(u64 a, u64 b){ return a<b?a:b; }
static __device__ __forceinline__ double shflx_f64(double v, int m) {
  u64 b = __double_as_longlong(v);
  return __longlong_as_double((long long)shflx_u64((u64)b, m));
}

// ---------------------------------------------------------------- K0: tables
__global__ __launch_bounds__(256) void k0_prep(const float* __restrict__ W,
    float* __restrict__ w2tab, float* __restrict__ c0tab,
    int* __restrict__ cnts, unsigned* __restrict__ minbits) {
  int wave = threadIdx.x >> 6, lane = threadIdx.x & 63;
  int k = blockIdx.x * 4 + wave;
  const float* wr = W + (size_t)k * DDIM;
  f32x4 a = *(const f32x4*)(wr + lane*4);
  double p = (double)a[0]*a[0] + (double)a[1]*a[1] + (double)a[2]*a[2] + (double)a[3]*a[3];
  #pragma unroll
  for (int off = 32; off; off >>= 1) p += __shfl_xor(p, off, 64);
  if (lane == 0) { w2tab[k] = (float)p; c0tab[k] = (float)(0.5 + 0.5*p); }
  if (blockIdx.x == 0) {
    if (threadIdx.x < NSHARD) cnts[threadIdx.x * 16] = 0;   // 64 B-strided counters
    if (threadIdx.x == NSHARD) *minbits = 0x7F800000u;
  }
}

// ------------------------------- K0b + K3 fused (independent block groups)
// blocks 0-127: Whf fragment f_lin = ct*512 + kc*64 + hi*16 + cc holds
//               fp16(-32*W[ct*16+cc][kc*32+hi*8 .. +7])
// blocks 128-639: codebook min pairwise distance (i-tile 32 x j-tile 64)
#define LDI 260
__global__ __launch_bounds__(256) void k0b_k3(const float* __restrict__ W,
    _Float16* __restrict__ Whf, const float* __restrict__ w2tab,
    unsigned* __restrict__ minbits) {
  __shared__ float si[32*LDI];                      // ~33 KB
  __shared__ float sj[16*LDI];                      // ~17 KB
  __shared__ float wmin[4];
  if (blockIdx.x < 128) {                           // ---- k0b: transpose
    int t = blockIdx.x * 256 + threadIdx.x;         // 0..32767
    int ct = t >> 9, f = t & 511;
    int kc = f >> 6, hi = (f >> 4) & 3, cc = f & 15;
    const float* src = W + (size_t)(ct*16 + cc) * DDIM + kc*32 + hi*8;
    f32x4 a = *(const f32x4*)src;
    f32x4 b = *(const f32x4*)(src + 4);
    h8 h;
    h[0]=(_Float16)(a[0]*WSCALE); h[1]=(_Float16)(a[1]*WSCALE);
    h[2]=(_Float16)(a[2]*WSCALE); h[3]=(_Float16)(a[3]*WSCALE);
    h[4]=(_Float16)(b[0]*WSCALE); h[5]=(_Float16)(b[1]*WSCALE);
    h[6]=(_Float16)(b[2]*WSCALE); h[7]=(_Float16)(b[3]*WSCALE);
    *(h8*)(Whf + (size_t)t * 8) = h;                // coalesced 16B/thread
    return;
  }
  // ---- k3: codebook distance
  int bid = blockIdx.x - 128;
  int bi = bid >> 4, bj = bid & 15;
  int i0 = bi * 32, j0 = bj * 64;
  for (int v = threadIdx.x; v < 32*64; v += 256) {  // coalesced si load
    int r = v >> 6, c = (v & 63) * 4;
    *(f32x4*)&si[r*LDI + c] = *(const f32x4*)(W + (size_t)(i0+r)*DDIM + c);
  }
  int ti = (threadIdx.x >> 4) * 2;                  // 2 i-rows
  int tj = threadIdx.x & 15;                        // 1 j-row per chunk
  float lmin = __uint_as_float(0x7F800000u);
  for (int ch = 0; ch < 4; ++ch) {
    __syncthreads();                                // sj safe to overwrite (+si ready)
    for (int v = threadIdx.x; v < 16*64; v += 256) {
      int r = v >> 6, c = (v & 63) * 4;
      *(f32x4*)&sj[r*LDI + c] = *(const f32x4*)(W + (size_t)(j0 + ch*16 + r)*DDIM + c);
    }
    __syncthreads();
    float d0 = 0.f, d1 = 0.f;
    for (int d = 0; d < DDIM; d += 4) {
      f32x4 jv = *(const f32x4*)&sj[tj*LDI + d];
      f32x4 a0 = *(const f32x4*)&si[ti*LDI + d];
      f32x4 a1 = *(const f32x4*)&si[(ti+1)*LDI + d];
      d0 += a0[0]*jv[0] + a0[1]*jv[1] + a0[2]*jv[2] + a0[3]*jv[3];
      d1 += a1[0]*jv[0] + a1[1]*jv[1] + a1[2]*jv[2] + a1[3]*jv[3];
    }
    int gj = j0 + ch*16 + tj;
    int gi0 = i0 + ti, gi1 = gi0 + 1;
    if (gi0 != gj) lmin = fminf(lmin, fmaxf(w2tab[gi0] + w2tab[gj] - 2.0f*d0, 0.0f));
    if (gi1 != gj) lmin = fminf(lmin, fmaxf(w2tab[gi1] + w2tab[gj] - 2.0f*d1, 0.0f));
  }
  #pragma unroll
  for (int off = 32; off; off >>= 1) lmin = fminf(lmin, __shfl_xor(lmin, off, 64));
  if ((threadIdx.x & 63) == 0) wmin[threadIdx.x >> 6] = lmin;
  __syncthreads();
  if (threadIdx.x == 0) {
    float m = fminf(fminf(wmin[0], wmin[1]), fminf(wmin[2], wmin[3]));
    atomicMin(minbits, __float_as_uint(m));
  }
}

// ---------------------------------------------------------------- K1: main
// 512 thr = 8 waves; wave owns 32 x-rows (2 tiles of 16); 16 periods x 4
// code-tiles. 8-buf ring (2 quads) + c0 = 68 KB -> 2 blocks/CU; grid 512.
// A = W' (codes), B = X (rows): C[code][xrow], lane: col=xrow=l&15, code=(l>>4)*4+r.
__global__ __launch_bounds__(512, 4) void k1_main(const float* __restrict__ X,
    const _Float16* __restrict__ Whf, const float* __restrict__ c0tab,
    const float* __restrict__ W, float* __restrict__ q,
    int4* __restrict__ list, int* __restrict__ cnts, int shard_cap) {
  __shared__ __align__(16) _Float16 lds[8][4096];  // 2 quads x 4 tiles x 8 KB
  __shared__ __align__(16) float c0s[KCODES];
  const int wave = threadIdx.x >> 6, lane = threadIdx.x & 63;
  const int col = lane & 15, hi = lane >> 4;
  const int rowbase = blockIdx.x * 256 + wave * (16*NT);

  // X rows -> fp16 fragments (B: col=l&15, k = (l>>4)*8 + j within 32-chunk)
  h8 xf[NT][8];
  #pragma unroll
  for (int t = 0; t < NT; ++t) {
    const float* xr = X + (size_t)(rowbase + t*16 + col) * DDIM + hi*8;
    #pragma unroll
    for (int kc = 0; kc < 8; ++kc) {
      f32x4 a = *(const f32x4*)(xr + kc*32);
      f32x4 b = *(const f32x4*)(xr + kc*32 + 4);
      h8 h;
      h[0]=(_Float16)(a[0]*XSCALE); h[1]=(_Float16)(a[1]*XSCALE);
      h[2]=(_Float16)(a[2]*XSCALE); h[3]=(_Float16)(a[3]*XSCALE);
      h[4]=(_Float16)(b[0]*XSCALE); h[5]=(_Float16)(b[1]*XSCALE);
      h[6]=(_Float16)(b[2]*XSCALE); h[7]=(_Float16)(b[3]*XSCALE);
      xf[t][kc] = h;
    }
  }

  unsigned m1[NT][4], m2[NT][4], m3[NT][4];  // per (tile,reg) slot top-3 keys
  #pragma unroll
  for (int t = 0; t < NT; ++t)
    #pragma unroll
    for (int r = 0; r < 4; ++r) { m1[t][r]=0xFFFFFFFFu; m2[t][r]=0xFFFFFFFFu; m3[t][r]=0xFFFFFFFFu; }

  // stage tile ct_ into buf: 512 fragments x 16 B; wave w covers fragments
  // [w*64, +64) -> ONE 16B gl_lds per wave; linear LDS dest, coalesced src.
  auto stage = [&](int buf, int ct_) {
    const _Float16* s0 = Whf + ((size_t)ct_*512 + wave*64 + lane)*8;
    __builtin_amdgcn_global_load_lds(
        (const __attribute__((address_space(1))) unsigned int*)s0,
        (__attribute__((address_space(3))) unsigned int*)&lds[buf][(wave*64)*8],
        16, 0, 0);
  };

  // prologue: c0 (waves 0-3) + quad 0 (tiles 0-3)
  if (wave < 4) {
    const float* c0src = c0tab + wave*256 + lane*4;
    __builtin_amdgcn_global_load_lds(
        (const __attribute__((address_space(1))) unsigned int*)c0src,
        (__attribute__((address_space(3))) unsigned int*)&c0s[wave*256],
        16, 0, 0);
  }
  stage(0, 0); stage(1, 1); stage(2, 2); stage(3, 3);
  asm volatile("s_waitcnt vmcnt(0)" ::: "memory");
  __builtin_amdgcn_s_barrier();

  const int lofs = (hi*16 + col) * 8;              // lane's fragment offset (elems)

  for (int p = 0; p < 16; ++p) {
    const int qb = (p & 1) * 4;                    // this quad's buffers
    if (p < 15) {                                  // stage next quad into other half
      const int nb = 4 - qb;
      stage(nb, 4*p + 4); stage(nb + 1, 4*p + 5);
      stage(nb + 2, 4*p + 6); stage(nb + 3, 4*p + 7);
    }

    #pragma unroll
    for (int u = 0; u < 4; ++u) {
      const int ct = 4*p + u;
      const _Float16* lb = &lds[qb + u][lofs];
      f32x4 c0 = *(const f32x4*)&c0s[ct*16 + hi*4];
      f32x4 acc0 = c0, acc1 = c0;                  // acc init = 0.5 + 0.5*w2
      h8 a0 = *(const h8*)(lb);                    // af rotation: 2 fragments live
      h8 a1 = *(const h8*)(lb + 64*8);
      __builtin_amdgcn_s_setprio(1);
      #pragma unroll
      for (int kc = 0; kc < 8; kc += 2) {
        h8 n0, n1;
        if (kc < 6) {
          n0 = *(const h8*)(lb + (kc+2)*64*8);
          n1 = *(const h8*)(lb + (kc+3)*64*8);
        }
        acc0 = __builtin_amdgcn_mfma_f32_16x16x32_f16(a0, xf[0][kc],   acc0, 0, 0, 0);
        acc1 = __builtin_amdgcn_mfma_f32_16x16x32_f16(a0, xf[1][kc],   acc1, 0, 0, 0);
        acc0 = __builtin_amdgcn_mfma_f32_16x16x32_f16(a1, xf[0][kc+1], acc0, 0, 0, 0);
        acc1 = __builtin_amdgcn_mfma_f32_16x16x32_f16(a1, xf[1][kc+1], acc1, 0, 0, 0);
        if (kc < 6) { a0 = n0; a1 = n1; }
      }
      __builtin_amdgcn_s_setprio(0);
      #pragma unroll
      for (int r = 0; r < 4; ++r) {
        // s = 0.5+0.5w2-dot in (0.44,0.56): positive -> uint-monotone.
        // low 6 bits hold ct (score quantum 64 ULP(0.5) = 3.8e-6).
        unsigned k0 = (__float_as_uint(acc0[r]) & ~63u) | (unsigned)ct;
        unsigned k1v = (__float_as_uint(acc1[r]) & ~63u) | (unsigned)ct;
        PUSH3(m1[0][r], m2[0][r], m3[0][r], k0);
        PUSH3(m1[1][r], m2[1][r], m3[1][r], k1v);
      }
    }
    if (p < 15) {                                  // quad staged this period must land
      asm volatile("s_waitcnt vmcnt(0)" ::: "memory");
      __builtin_amdgcn_s_barrier();
    }
  }

  // ---- merge: slot top-3 -> u64 (scorebits<<32 | code) -> row top-4 ----
  u64 T1[NT], T2[NT], T3[NT], T4[NT];
  #pragma unroll
  for (int t = 0; t < NT; ++t) {
    u64 t1=~0ULL, t2=~0ULL, t3=~0ULL, t4=~0ULL;
    #pragma unroll
    for (int r = 0; r < 4; ++r) {
      unsigned ks[3] = { m1[t][r], m2[t][r], m3[t][r] };
      #pragma unroll
      for (int m = 0; m < 3; ++m) {
        unsigned key = ks[m];
        unsigned code = (key & 63u)*16u + (unsigned)(hi*4 + r);
        u64 k64 = ((u64)(key & ~63u) << 32) | code;
        PUSH4(t1,t2,t3,t4,k64);
      }
    }
    #pragma unroll
    for (int dd = 16; dd <= 32; dd <<= 1) {
      u64 o1=shflx_u64(t1,dd), o2=shflx_u64(t2,dd), o3=shflx_u64(t3,dd), o4=shflx_u64(t4,dd);
      PUSH4(t1,t2,t3,t4,o1); PUSH4(t1,t2,t3,t4,o2);
      PUSH4(t1,t2,t3,t4,o3); PUSH4(t1,t2,t3,t4,o4);
    }
    T1[t]=t1; T2[t]=t2; T3[t]=t3; T4[t]=t4;
  }

  // Phase 1: per-row slow flags (wave-uniform bitmask, 1 bit per row c=0..15)
  unsigned smask[NT]; unsigned win[NT];
  #pragma unroll
  for (int t = 0; t < NT; ++t) {
    float f1 = __uint_as_float((unsigned)(T1[t]>>32));
    float f2 = __uint_as_float((unsigned)(T2[t]>>32));
    win[t] = (unsigned)T1[t] & 1023u;
    smask[t] = (unsigned)(__ballot(f2 - f1 <= EPS) & 0xFFFFull);
  }

  // Phase 2: one batched atomic per wave; single-lane entry stores (rare)
  int nslow = __popc(smask[0]) + __popc(smask[1]);
  const int shard = (blockIdx.x * 8 + wave) & (NSHARD - 1);
  int* cnt = cnts + shard * 16;
  int base = 0;
  if (nslow) {
    if (lane == 0) base = atomicAdd(cnt, nslow);
    base = __shfl(base, 0, 64);
  }
  int idx = 0;
  #pragma unroll
  for (int t = 0; t < NT; ++t) {
    unsigned m = smask[t];
    while (m) {
      int c = __builtin_ctz(m); m &= m - 1;
      int pos = base + idx;
      if (pos < shard_cap && lane == c) {
        unsigned c1 = (unsigned)T1[t] & 1023u, c2 = (unsigned)T2[t] & 1023u;
        unsigned c3 = (unsigned)T3[t] & 1023u, c4 = (unsigned)T4[t] & 1023u;
        size_t e = ((size_t)shard * shard_cap + pos) * 2;
        list[e]   = make_int4(rowbase + t*16 + c, (int)(unsigned)(T1[t]>>32),
                              (int)(unsigned)(T2[t]>>32), (int)(unsigned)(T3[t]>>32));
        list[e+1] = make_int4((int)(unsigned)(T4[t]>>32),
                              (int)(c1 | (c2<<10) | (c3<<20)), (int)c4, 0);
      }
      idx++;
    }
  }

  // Phase 3: pre-broadcast all 32 winners, then independent pipelined gathers.
  // Slow rows get the provisional winner; k2 overwrites them.
  unsigned wbc[NT][16];
  #pragma unroll
  for (int t = 0; t < NT; ++t)
    #pragma unroll
    for (int c = 0; c < 16; ++c)
      wbc[t][c] = (unsigned)__shfl((int)win[t], c, 64);
  #pragma unroll
  for (int t = 0; t < NT; ++t)
    #pragma unroll
    for (int c = 0; c < 16; ++c) {
      f32x4 wv = *(const f32x4*)(W + (size_t)wbc[t][c]*DDIM + lane*4);
      *(f32x4*)(q + (size_t)(rowbase + t*16 + c)*DDIM + lane*4) = wv;
    }
}

// ---------------------------------------------------------------- K2: fixup (+k4)
__global__ __launch_bounds__(256) void k2_fix(const float* __restrict__ X,
    const float* __restrict__ W, const float* __restrict__ w2tab,
    float* __restrict__ q, const int4* __restrict__ list,
    const int* __restrict__ cnts, int shard_cap,
    const unsigned* __restrict__ minbits, float* __restrict__ outscalar) {
  if (blockIdx.x == 0 && threadIdx.x == 0)          // k3 done (prior launch)
    *outscalar = sqrtf(__uint_as_float(*minbits));
  __shared__ float xs[4][DDIM];
  const int wave = threadIdx.x >> 6, lane = threadIdx.x & 63;
  const int wgid = blockIdx.x * 4 + wave;
  const int shard = wgid & (NSHARD - 1);
  const int start = wgid >> 6;                    // NSHARD==64
  const int step  = (gridDim.x * 4) >> 6;
  int cnt = cnts[shard * 16]; if (cnt > shard_cap) cnt = shard_cap;

  for (int i = start; i < cnt; i += step) {
    size_t e = ((size_t)shard * shard_cap + i) * 2;
    int4 e0 = list[e], e1 = list[e + 1];
    int row = e0.x;
    float f1 = __uint_as_float((unsigned)e0.y);
    float f2 = __uint_as_float((unsigned)e0.z);
    float f3 = __uint_as_float((unsigned)e0.w);
    float f4 = __uint_as_float((unsigned)e1.x);
    unsigned cpack = (unsigned)e1.y;

    const float* xr = X + (size_t)row * DDIM;
    f32x4 xv = *(const f32x4*)(xr + lane*4);
    // x2 like np: square in fp32, sum exactly (f64), round once
    double x2d = (double)(xv[0]*xv[0]) + (double)(xv[1]*xv[1])
               + (double)(xv[2]*xv[2]) + (double)(xv[3]*xv[3]);

    if (f4 - f1 <= EPS) {
      // full scan: every code, f64 dot (4-way ILP), np-replicated quantization
      #pragma unroll
      for (int off = 32; off; off >>= 1) x2d += shflx_f64(x2d, off);
      float x2f = (float)x2d;
      *(f32x4*)&xs[wave][lane*4] = xv;
      u64 best = ~0ULL;
      for (int c = lane; c < KCODES; c += 64) {
        const float* wr = W + (size_t)c * DDIM;
        double p0 = 0.0, p1 = 0.0, p2 = 0.0, p3 = 0.0;   // 4 independent chains
        for (int d = 0; d < DDIM; d += 16) {
          f32x4 w0 = *(const f32x4*)(wr + d);
          f32x4 w1 = *(const f32x4*)(wr + d + 4);
          f32x4 w2 = *(const f32x4*)(wr + d + 8);
          f32x4 w3 = *(const f32x4*)(wr + d + 12);
          p0 += (double)w0[0]*xs[wave][d]    + (double)w0[1]*xs[wave][d+1]
              + (double)w0[2]*xs[wave][d+2]  + (double)w0[3]*xs[wave][d+3];
          p1 += (double)w1[0]*xs[wave][d+4]  + (double)w1[1]*xs[wave][d+5]
              + (double)w1[2]*xs[wave][d+6]  + (double)w1[3]*xs[wave][d+7];
          p2 += (double)w2[0]*xs[wave][d+8]  + (double)w2[1]*xs[wave][d+9]
              + (double)w2[2]*xs[wave][d+10] + (double)w2[3]*xs[wave][d+11];
          p3 += (double)w3[0]*xs[wave][d+12] + (double)w3[1]*xs[wave][d+13]
              + (double)w3[2]*xs[wave][d+14] + (double)w3[3]*xs[wave][d+15];
        }
        float dotf = (float)((p0 + p1) + (p2 + p3));
        float dval = (x2f + w2tab[c]) - 2.0f*dotf;
        best = u64mn(best, ((u64)__float_as_uint(dval) << 32) | (unsigned)c);
      }
      #pragma unroll
      for (int off = 32; off; off >>= 1) best = u64mn(best, shflx_u64(best, off));
      unsigned win = (unsigned)best & 1023u;
      f32x4 wv = *(const f32x4*)(W + (size_t)win*DDIM + lane*4);
      *(f32x4*)(q + (size_t)row*DDIM + lane*4) = wv;
    } else {
      // always rescore 3 candidates (pad duplicates) with 4-way-ILP butterflies
      unsigned ca = cpack & 1023u;
      unsigned cb = (f2 - f1 <= EPS) ? ((cpack>>10) & 1023u) : ca;
      unsigned cc = (f3 - f1 <= EPS) ? ((cpack>>20) & 1023u) : ca;
      f32x4 wa = *(const f32x4*)(W + (size_t)ca*DDIM + lane*4);
      f32x4 wb = *(const f32x4*)(W + (size_t)cb*DDIM + lane*4);
      f32x4 wc = *(const f32x4*)(W + (size_t)cc*DDIM + lane*4);
      double da = (double)xv[0]*wa[0] + (double)xv[1]*wa[1]
                + (double)xv[2]*wa[2] + (double)xv[3]*wa[3];
      double db = (double)xv[0]*wb[0] + (double)xv[1]*wb[1]
                + (double)xv[2]*wb[2] + (double)xv[3]*wb[3];
      double dc = (double)xv[0]*wc[0] + (double)xv[1]*wc[1]
                + (double)xv[2]*wc[2] + (double)xv[3]*wc[3];
      #pragma unroll
      for (int off = 32; off; off >>= 1) {          // 4 interleaved chains
        x2d += shflx_f64(x2d, off);
        da  += shflx_f64(da,  off);
        db  += shflx_f64(db,  off);
        dc  += shflx_f64(dc,  off);
      }
      float x2f = (float)x2d;
      float va = (x2f + w2tab[ca]) - 2.0f*(float)da;   // np's expression, fp32
      float vb = (x2f + w2tab[cb]) - 2.0f*(float)db;
      float vc = (x2f + w2tab[cc]) - 2.0f*(float)dc;
      u64 best = ((u64)__float_as_uint(va) << 32) | ca;  // tie -> lower index
      best = u64mn(best, ((u64)__float_as_uint(vb) << 32) | cb);
      best = u64mn(best, ((u64)__float_as_uint(vc) << 32) | cc);
      unsigned win = (unsigned)best & 1023u;
      f32x4 wv = *(const f32x4*)(W + (size_t)win*DDIM + lane*4);
      *(f32x4*)(q + (size_t)row*DDIM + lane*4) = wv;
    }
  }
}

// ---------------------------------------------------------------- launch
extern "C" void kernel_launch(void* const* d_in, const int* in_sizes, int n_in,
                              void* d_out, int out_size, void* d_ws, size_t ws_size,
                              hipStream_t stream) {
  const float* X = (const float*)d_in[0];
  const float* W = (const float*)d_in[1];
  float* out = (float*)d_out;
  char* ws = (char*)d_ws;

  unsigned* minbits = (unsigned*)(ws + WS_MIN);
  int* cnts = (int*)(ws + WS_CNTS);
  float* w2tab = (float*)(ws + WS_W2);
  float* c0tab = (float*)(ws + WS_C0);
  _Float16* Whf = (_Float16*)(ws + WS_WH);
  int4* list = (int4*)(ws + WS_LIST);

  long long cap_ll = ((long long)ws_size - (long long)WS_LIST) / (NSHARD * 32);
  if (cap_ll < 0) cap_ll = 0;
  if (cap_ll > NROWS) cap_ll = NROWS;
  int shard_cap = (int)cap_ll;

  k0_prep<<<KCODES/4, 256, 0, stream>>>(W, w2tab, c0tab, cnts, minbits);
  k0b_k3<<<128 + 512, 256, 0, stream>>>(W, Whf, w2tab, minbits);
  k1_main<<<NROWS/256, 512, 0, stream>>>(X, Whf, c0tab, W, out, list, cnts, shard_cap);
  k2_fix<<<1024, 256, 0, stream>>>(X, W, w2tab, out, list, cnts, shard_cap,
                                   minbits, out + (size_t)NROWS*DDIM);
}